// Round 3
// baseline (121.242 us; speedup 1.0000x reference)
//
#include <hip/hip_runtime.h>
#include <math.h>

#define NNV 4096   // N
#define KKV 64     // K
#define BBV 256    // B
#define CHN 256    // n-chunk staged in LDS
#define NCH (NNV / CHN)

typedef unsigned short u16;
typedef unsigned int u32;
typedef u32  u32x4  __attribute__((ext_vector_type(4)));
typedef short bf16x8 __attribute__((ext_vector_type(8)));
typedef float f32x4  __attribute__((ext_vector_type(4)));
typedef float f32x16 __attribute__((ext_vector_type(16)));

__device__ inline u16 f2bf(float x) {           // RNE f32 -> bf16
    u32 u = __float_as_uint(x);
    u = u + 0x7FFFu + ((u >> 16) & 1u);
    return (u16)(u >> 16);
}

__device__ inline float rlane(float v, int l) { // wave-uniform readlane broadcast
    return __uint_as_float(__builtin_amdgcn_readlane(__float_as_uint(v), l));
}

// ================= K1: elementwise prep (+ Cs build in blocks 256..319) ===========
__global__ __launch_bounds__(256) void prep(
    const float* __restrict__ targets, const float* __restrict__ rho,
    const float* __restrict__ qs, const float* __restrict__ means,
    const float* __restrict__ C, const float* __restrict__ psi,
    u16* __restrict__ Csbf, u16* __restrict__ dsbf,
    u32* __restrict__ mask2, float* __restrict__ scal) {
    const int blk = blockIdx.x;
    const int t = threadIdx.x;

    if (blk >= BBV) {                    // Cs = C * rsqrt(psi), bf16, row-major [64][4096]
        const int k = blk - BBV;
        const float* Crow = C + (size_t)k * NNV;
        u16* Orow = Csbf + (size_t)k * NNV;
        const int base = t * 16;
#pragma unroll
        for (int j = 0; j < 16; j += 4) {
            float4 cv = *(const float4*)(Crow + base + j);
            float4 pv = *(const float4*)(psi + base + j);
            u32 w0 = (u32)f2bf(cv.x * rsqrtf(pv.x)) | ((u32)f2bf(cv.y * rsqrtf(pv.y)) << 16);
            u32 w1 = (u32)f2bf(cv.z * rsqrtf(pv.z)) | ((u32)f2bf(cv.w * rsqrtf(pv.w)) << 16);
            *(uint2*)(Orow + base + j) = make_uint2(w0, w1);
        }
        return;
    }

    __shared__ float sred[4][5];
    const int b = blk;
    const int lane = t & 63, wid = t >> 6;
    const float rho_s = rho[0];
    const float lrho = __logf(rho_s);
    const int base = t * 16;
    const float* tg = targets + (size_t)b * NNV + base;
    const float* qb = qs + (size_t)b * NNV + base;
    const float* mb = means + (size_t)b * NNV + base;
    const float* pb = psi + base;

    float tvv[16], qv[16], muv[16], pv[16];
#pragma unroll
    for (int j = 0; j < 16; j += 4) {
        *(float4*)(tvv + j) = *(const float4*)(tg + j);
        *(float4*)(qv + j)  = *(const float4*)(qb + j);
        *(float4*)(muv + j) = *(const float4*)(mb + j);
        *(float4*)(pv + j)  = *(const float4*)(pb + j);
    }

    float s_uni = 0.f, s_wdd = 0.f, s_nb = 0.f, s_mlp = 0.f, s_extra = 0.f;
    u16 dsv[16]; bool mk[16];
#pragma unroll
    for (int j = 0; j < 16; ++j) {
        bool m = tvv[j] >= rho_s;
        float ds = 0.f;
        if (m) {
            float y = __logf(tvv[j]);
            float d = y - muv[j];
            ds = d * rsqrtf(pv[j]);               // ds^2 = w*d^2
            s_wdd += ds * ds;
            s_nb += 1.f;
            s_mlp += __logf(pv[j]);
            s_extra += __logf(qv[j]) - y;
        } else {
            s_uni += __logf(1.f - qv[j]) - lrho;
        }
        dsv[j] = f2bf(ds);
        mk[j] = m;
    }
    u32 mw[8], dp[8];
#pragma unroll
    for (int i = 0; i < 8; ++i) {
        mw[i] = (mk[2*i] ? 0xFFFFu : 0u) | (mk[2*i+1] ? 0xFFFF0000u : 0u);
        dp[i] = (u32)dsv[2*i] | ((u32)dsv[2*i+1] << 16);
    }
    *(u32x4*)(dsbf + (size_t)b * NNV + base)     = ((u32x4*)dp)[0];
    *(u32x4*)(dsbf + (size_t)b * NNV + base + 8) = ((u32x4*)dp)[1];
    *(u32x4*)(mask2 + (size_t)b * (NNV/2) + t*8)     = ((u32x4*)mw)[0];
    *(u32x4*)(mask2 + (size_t)b * (NNV/2) + t*8 + 4) = ((u32x4*)mw)[1];

#pragma unroll
    for (int off = 32; off > 0; off >>= 1) {
        s_uni  += __shfl_down(s_uni, off);
        s_wdd  += __shfl_down(s_wdd, off);
        s_nb   += __shfl_down(s_nb, off);
        s_mlp  += __shfl_down(s_mlp, off);
        s_extra+= __shfl_down(s_extra, off);
    }
    if (lane == 0) {
        sred[wid][0] = s_uni; sred[wid][1] = s_wdd; sred[wid][2] = s_nb;
        sred[wid][3] = s_mlp; sred[wid][4] = s_extra;
    }
    __syncthreads();
    if (t == 0) {
        float a0=0,a1=0,a2=0,a3=0,a4=0;
#pragma unroll
        for (int w4 = 0; w4 < 4; ++w4) {
            a0 += sred[w4][0]; a1 += sred[w4][1]; a2 += sred[w4][2];
            a3 += sred[w4][3]; a4 += sred[w4][4];
        }
        scal[b*5+0]=a0; scal[b*5+1]=a1; scal[b*5+2]=a2; scal[b*5+3]=a3; scal[b*5+4]=a4;
    }
}

// ============ K2: per-batch Gram via MFMA + fused register Cholesky/solve ============
__global__ __launch_bounds__(512) void gram_fused(
    const u16* __restrict__ Csbf, const u16* __restrict__ dsbf,
    const u32* __restrict__ mask2g, const float* __restrict__ scal,
    float* __restrict__ out) {
    __shared__ __align__(16) u16 gbuf[2][KKV * CHN];   // swizzled Cs chunk, 32 KB each
    __shared__ __align__(16) u16 dsrow[2][CHN];
    __shared__ __align__(16) u32 m2[NNV / 2];          // packed bf16-pair masks, 8 KB

    const int b = blockIdx.x;
    const int t = threadIdx.x;
    const int lane = t & 63;
    const int w = t >> 6;
    const int half = w & 1;
    const int tilid = w >> 1;          // 0,1,2 = A00,A10,A11 ; 3 = u-waves
    const int l31 = lane & 31;
    const int hsel = lane >> 5;

    {   // stage full-batch mask words
        u32x4 v = *(const u32x4*)(mask2g + (size_t)b * (NNV/2) + t*4);
        *(u32x4*)(m2 + t*4) = v;
    }

    f32x16 acc;
#pragma unroll
    for (int i = 0; i < 16; ++i) acc[i] = 0.f;
    f32x4 ua, ubv;
#pragma unroll
    for (int i = 0; i < 4; ++i) { ua[i] = 0.f; ubv[i] = 0.f; }

#define STAGE(cc, pp) do {                                                          \
    _Pragma("unroll")                                                               \
    for (int i_ = 0; i_ < 4; ++i_) {                                                \
        int beta0 = w*256 + i_*64;                                                  \
        int beta = beta0 + lane;                                                    \
        int r_ = beta >> 5, blkP = beta & 31;                                       \
        int blkS = blkP ^ (r_ & 15);   /* source pre-swizzle (m173 pattern) */      \
        const u16* src = Csbf + (size_t)r_ * NNV + (cc)*CHN + blkS*8;               \
        __builtin_amdgcn_global_load_lds(                                           \
            (const __attribute__((address_space(1))) void*)src,                     \
            (__attribute__((address_space(3))) void*)(&gbuf[pp][beta0*8]),          \
            16, 0, 0);                                                              \
    }                                                                               \
    if (w == 7 && lane < 32) {                                                      \
        u32x4 dv_ = *(const u32x4*)(dsbf + (size_t)b * NNV + (cc)*CHN + lane*8);    \
        *(u32x4*)(&dsrow[pp][lane*8]) = dv_;                                        \
    }                                                                               \
} while (0)

    STAGE(0, 0);
    __syncthreads();

    for (int c = 0; c < NCH; ++c) {
        const int p = c & 1;
        if (c + 1 < NCH) STAGE(c + 1, p ^ 1);
        const char* gb = (const char*)gbuf[p];
        if (w < 6) {
            const int rbA = (tilid == 0) ? 0 : 32;
            const int rbB = (tilid == 2) ? 32 : 0;
            const int rA = rbA + l31, rB = rbB + l31;
            const int swA = (rA & 15) << 4, swB = (rB & 15) << 4;
            const char* mbase = (const char*)m2 + c*512 + hsel*16;
#pragma unroll
            for (int s8 = 0; s8 < 8; ++s8) {
                const int s = half*8 + s8;
                const int colbyte = s*32 + hsel*16;
                u32x4 fB = *(const u32x4*)(gb + rB*512 + (colbyte ^ swB));
                u32x4 fA;
                if (tilid == 1) fA = *(const u32x4*)(gb + rA*512 + (colbyte ^ swA));
                else            fA = fB;                       // diag tiles: reuse read
                u32x4 mkv = *(const u32x4*)(mbase + s*32);     // broadcast per half-wave
                fA = fA & mkv;                                  // mask A-side only (m^2=m)
                acc = __builtin_amdgcn_mfma_f32_32x32x16_bf16(
                        __builtin_bit_cast(bf16x8, fA),
                        __builtin_bit_cast(bf16x8, fB), acc, 0, 0, 0);
            }
        } else {
            const int cb0 = (w == 6) ? 0 : 32;
            const int l15 = lane & 15;
            const int g4 = lane >> 4;
            const int r0 = cb0 + l15, r1 = r0 + 16;
            const int sw0 = (r0 & 15) << 4, sw1 = (r1 & 15) << 4;
            const char* dr = (const char*)dsrow[p];
#pragma unroll
            for (int su = 0; su < 8; ++su) {
                const int colbyte = su*64 + g4*16;
                u32x4 dv = *(const u32x4*)(dr + colbyte);      // broadcast
                if (l15 != 0) dv = dv ^ dv;                    // A rows 1..15 = 0
                u32x4 f0 = *(const u32x4*)(gb + r0*512 + (colbyte ^ sw0));
                u32x4 f1 = *(const u32x4*)(gb + r1*512 + (colbyte ^ sw1));
                ua  = __builtin_amdgcn_mfma_f32_16x16x32_bf16(
                        __builtin_bit_cast(bf16x8, dv), __builtin_bit_cast(bf16x8, f0), ua, 0,0,0);
                ubv = __builtin_amdgcn_mfma_f32_16x16x32_bf16(
                        __builtin_bit_cast(bf16x8, dv), __builtin_bit_cast(bf16x8, f1), ubv, 0,0,0);
            }
        }
        __syncthreads();
    }

    // ---- epilogue: combine n-halves into LDS A (stride 65) + LDS u ----
    float* red  = (float*)&gbuf[0][0];      // 12 KB reduction buffer
    float* ACs  = (float*)&gbuf[1][0];      // 64x65 f32 A matrix
    float* ubuf = (float*)&m2[0];           // 64 f32 u vector
    if (w < 6 && half == 0) {
#pragma unroll
        for (int g = 0; g < 16; ++g) {
            int row = (g & 3) + 8*(g >> 2) + 4*hsel;          // 32x32 C/D layout (m74/m101)
            red[tilid*1024 + row*32 + l31] = acc[g];
        }
    }
    if (w >= 6 && lane < 16) {                                 // 16x16 D row0 = u
        const int cb0 = (w == 6) ? 0 : 32;
        ubuf[cb0 + lane]      = ua[0];
        ubuf[cb0 + 16 + lane] = ubv[0];
    }
    __syncthreads();
    if (w < 6 && half == 1) {
#pragma unroll
        for (int g = 0; g < 16; ++g) {
            int row = (g & 3) + 8*(g >> 2) + 4*hsel;
            float v = red[tilid*1024 + row*32 + l31] + acc[g];
            int gr = (tilid == 0) ? row : 32 + row;
            int gc = (tilid == 2) ? 32 + l31 : l31;
            ACs[gr*65 + gc] = v;                               // lower triangle complete
        }
    }
    __syncthreads();

    // ---- wave 0: register-resident left-looking Cholesky + solve + assembly ----
    if (w == 0) {
        float Lrow[64];
        float dval = 1.f, invd = 0.f;
        float ubr = ubuf[lane];

        // A(+I) rows: direct LDS reads, compiler hoists/schedules (no LDS writes below)
#pragma unroll
        for (int j = 0; j < 64; ++j) {
            float a = ACs[lane*65 + j];
            if (lane == j) a += 1.0f;
            // left-looking column j: subtract sum_{k<j} L[i][k] * L[j][k]
#pragma unroll
            for (int k = 0; k < 64; ++k) {
                if (k < j) {
                    float bjk = rlane(Lrow[k], j);   // L[j][k], wave-uniform
                    a -= Lrow[k] * bjk;
                }
            }
            float dv = rlane(a, j);                  // = Ljj^2
            float invs = rsqrtf(dv);
            if (lane == j) { dval = dv; invd = invs; }
            Lrow[j] = (lane > j) ? a * invs : 0.f;   // strict lower col j (diag excluded)
        }

        // forward solve L z = u, z2 = ||z||^2 (lane-uniform)
        float z2 = 0.f;
#pragma unroll
        for (int j = 0; j < 64; ++j) {
            float zj = rlane(ubr, j) * rlane(invd, j);
            z2 += zj * zj;
            ubr -= Lrow[j] * zj;                     // Lrow[j]=0 for lane<=j
        }

        // logdetA = sum_j log(Ljj^2): one log per lane + butterfly
        float ld = __logf(dval);
#pragma unroll
        for (int off = 32; off > 0; off >>= 1) ld += __shfl_xor(ld, off);

        if (lane == 0) {
            float uni = scal[b*5+0], wdd = scal[b*5+1], nb = scal[b*5+2],
                  mlp = scal[b*5+3], extra = scal[b*5+4];
            const float LOG2PI = 1.8378770664093453f;
            out[b] = uni + extra - 0.5f * (nb * LOG2PI + mlp + ld + (wdd - z2));
        }
    }
#undef STAGE
}

extern "C" void kernel_launch(void* const* d_in, const int* in_sizes, int n_in,
                              void* d_out, int out_size, void* d_ws, size_t ws_size,
                              hipStream_t stream) {
    const float* targets = (const float*)d_in[0];
    const float* rho     = (const float*)d_in[1];
    const float* qs      = (const float*)d_in[2];
    const float* means   = (const float*)d_in[3];
    const float* C       = (const float*)d_in[4];
    const float* psi     = (const float*)d_in[5];
    float* out = (float*)d_out;

    char* ws = (char*)d_ws;
    u16* Csbf  = (u16*)(ws);                                      // 512 KB
    u16* dsbf  = (u16*)(ws + 0x80000);                            // 2 MB
    u32* mask2 = (u32*)(ws + 0x280000);                           // 2 MB
    float* scal = (float*)(ws + 0x480000);                        // 5 KB

    prep<<<BBV + KKV, 256, 0, stream>>>(targets, rho, qs, means, C, psi,
                                        Csbf, dsbf, mask2, scal);
    gram_fused<<<BBV, 512, 0, stream>>>(Csbf, dsbf, mask2, scal, out);
}

// Round 4
// 48.545 us; speedup vs baseline: 2.4975x; 2.4975x over previous
//
#include <hip/hip_runtime.h>
#include <math.h>

#define NNV 4096   // N
#define KKV 64     // K
#define BBV 256    // B
#define CHN 256    // n-chunk staged in LDS
#define NCH (NNV / CHN)

typedef unsigned short u16;
typedef unsigned int u32;
typedef u32  u32x4  __attribute__((ext_vector_type(4)));
typedef short bf16x8 __attribute__((ext_vector_type(8)));
typedef float f32x4  __attribute__((ext_vector_type(4)));
typedef float f32x16 __attribute__((ext_vector_type(16)));

__device__ inline u16 f2bf(float x) {           // RNE f32 -> bf16
    u32 u = __float_as_uint(x);
    u = u + 0x7FFFu + ((u >> 16) & 1u);
    return (u16)(u >> 16);
}

__device__ inline float rlane(float v, int l) { // wave-uniform readlane broadcast
    return __uint_as_float(__builtin_amdgcn_readlane(__float_as_uint(v), l));
}

// ================= K1: elementwise prep (+ Cs build in blocks 256..319) ===========
__global__ __launch_bounds__(256) void prep(
    const float* __restrict__ targets, const float* __restrict__ rho,
    const float* __restrict__ qs, const float* __restrict__ means,
    const float* __restrict__ C, const float* __restrict__ psi,
    u16* __restrict__ Csbf, u16* __restrict__ dsbf,
    u32* __restrict__ mask2, float* __restrict__ scal) {
    const int blk = blockIdx.x;
    const int t = threadIdx.x;

    if (blk >= BBV) {                    // Cs = C * rsqrt(psi), bf16, row-major [64][4096]
        const int k = blk - BBV;
        const float* Crow = C + (size_t)k * NNV;
        u16* Orow = Csbf + (size_t)k * NNV;
        const int base = t * 16;
#pragma unroll
        for (int j = 0; j < 16; j += 4) {
            float4 cv = *(const float4*)(Crow + base + j);
            float4 pv = *(const float4*)(psi + base + j);
            u32 w0 = (u32)f2bf(cv.x * rsqrtf(pv.x)) | ((u32)f2bf(cv.y * rsqrtf(pv.y)) << 16);
            u32 w1 = (u32)f2bf(cv.z * rsqrtf(pv.z)) | ((u32)f2bf(cv.w * rsqrtf(pv.w)) << 16);
            *(uint2*)(Orow + base + j) = make_uint2(w0, w1);
        }
        return;
    }

    __shared__ float sred[4][5];
    const int b = blk;
    const int lane = t & 63, wid = t >> 6;
    const float rho_s = rho[0];
    const float lrho = __logf(rho_s);
    const int base = t * 16;
    const float* tg = targets + (size_t)b * NNV + base;
    const float* qb = qs + (size_t)b * NNV + base;
    const float* mb = means + (size_t)b * NNV + base;
    const float* pb = psi + base;

    float tvv[16], qv[16], muv[16], pv[16];
#pragma unroll
    for (int j = 0; j < 16; j += 4) {
        *(float4*)(tvv + j) = *(const float4*)(tg + j);
        *(float4*)(qv + j)  = *(const float4*)(qb + j);
        *(float4*)(muv + j) = *(const float4*)(mb + j);
        *(float4*)(pv + j)  = *(const float4*)(pb + j);
    }

    float s_uni = 0.f, s_wdd = 0.f, s_nb = 0.f, s_mlp = 0.f, s_extra = 0.f;
    u16 dsv[16]; bool mk[16];
#pragma unroll
    for (int j = 0; j < 16; ++j) {
        bool m = tvv[j] >= rho_s;
        float ds = 0.f;
        if (m) {
            float y = __logf(tvv[j]);
            float d = y - muv[j];
            ds = d * rsqrtf(pv[j]);               // ds^2 = w*d^2
            s_wdd += ds * ds;
            s_nb += 1.f;
            s_mlp += __logf(pv[j]);
            s_extra += __logf(qv[j]) - y;
        } else {
            s_uni += __logf(1.f - qv[j]) - lrho;
        }
        dsv[j] = f2bf(ds);
        mk[j] = m;
    }
    u32 mw[8], dp[8];
#pragma unroll
    for (int i = 0; i < 8; ++i) {
        mw[i] = (mk[2*i] ? 0xFFFFu : 0u) | (mk[2*i+1] ? 0xFFFF0000u : 0u);
        dp[i] = (u32)dsv[2*i] | ((u32)dsv[2*i+1] << 16);
    }
    *(u32x4*)(dsbf + (size_t)b * NNV + base)     = ((u32x4*)dp)[0];
    *(u32x4*)(dsbf + (size_t)b * NNV + base + 8) = ((u32x4*)dp)[1];
    *(u32x4*)(mask2 + (size_t)b * (NNV/2) + t*8)     = ((u32x4*)mw)[0];
    *(u32x4*)(mask2 + (size_t)b * (NNV/2) + t*8 + 4) = ((u32x4*)mw)[1];

#pragma unroll
    for (int off = 32; off > 0; off >>= 1) {
        s_uni  += __shfl_down(s_uni, off);
        s_wdd  += __shfl_down(s_wdd, off);
        s_nb   += __shfl_down(s_nb, off);
        s_mlp  += __shfl_down(s_mlp, off);
        s_extra+= __shfl_down(s_extra, off);
    }
    if (lane == 0) {
        sred[wid][0] = s_uni; sred[wid][1] = s_wdd; sred[wid][2] = s_nb;
        sred[wid][3] = s_mlp; sred[wid][4] = s_extra;
    }
    __syncthreads();
    if (t == 0) {
        float a0=0,a1=0,a2=0,a3=0,a4=0;
#pragma unroll
        for (int w4 = 0; w4 < 4; ++w4) {
            a0 += sred[w4][0]; a1 += sred[w4][1]; a2 += sred[w4][2];
            a3 += sred[w4][3]; a4 += sred[w4][4];
        }
        scal[b*5+0]=a0; scal[b*5+1]=a1; scal[b*5+2]=a2; scal[b*5+3]=a3; scal[b*5+4]=a4;
    }
}

// ================= K2: per-batch Gram via MFMA (R2-proven structure) ===========
// G = [m ? Cs : 0 (64 rows); ds]; computes A00,A10,A11 (32x32 tiles) and u (row64).
__global__ __launch_bounds__(512) void gram(
    const u16* __restrict__ Csbf, const u16* __restrict__ dsbf,
    const u32* __restrict__ mask2g, float* __restrict__ Abuf, float* __restrict__ Uf) {
    __shared__ __align__(16) u16 gbuf[2][KKV * CHN];   // swizzled Cs chunk, 32 KB each
    __shared__ __align__(16) u16 dsrow[2][CHN];
    __shared__ __align__(16) u32 m2[NNV / 2];          // packed bf16-pair masks, 8 KB

    const int b = blockIdx.x;
    const int t = threadIdx.x;
    const int lane = t & 63;
    const int w = t >> 6;
    const int half = w & 1;
    const int tilid = w >> 1;          // 0,1,2 = A00,A10,A11 ; 3 = u-waves
    const int l31 = lane & 31;
    const int hsel = lane >> 5;

    {   // stage full-batch mask words
        u32x4 v = *(const u32x4*)(mask2g + (size_t)b * (NNV/2) + t*4);
        *(u32x4*)(m2 + t*4) = v;
    }

    f32x16 acc;
#pragma unroll
    for (int i = 0; i < 16; ++i) acc[i] = 0.f;
    f32x4 ua, ubv;
#pragma unroll
    for (int i = 0; i < 4; ++i) { ua[i] = 0.f; ubv[i] = 0.f; }

#define STAGE(cc, pp) do {                                                          \
    _Pragma("unroll")                                                               \
    for (int i_ = 0; i_ < 4; ++i_) {                                                \
        int beta0 = w*256 + i_*64;                                                  \
        int beta = beta0 + lane;                                                    \
        int r_ = beta >> 5, blkP = beta & 31;                                       \
        int blkS = blkP ^ (r_ & 15);   /* source pre-swizzle (m173 pattern) */      \
        const u16* src = Csbf + (size_t)r_ * NNV + (cc)*CHN + blkS*8;               \
        __builtin_amdgcn_global_load_lds(                                           \
            (const __attribute__((address_space(1))) void*)src,                     \
            (__attribute__((address_space(3))) void*)(&gbuf[pp][beta0*8]),          \
            16, 0, 0);                                                              \
    }                                                                               \
    if (w == 7 && lane < 32) {                                                      \
        u32x4 dv_ = *(const u32x4*)(dsbf + (size_t)b * NNV + (cc)*CHN + lane*8);    \
        *(u32x4*)(&dsrow[pp][lane*8]) = dv_;                                        \
    }                                                                               \
} while (0)

    STAGE(0, 0);
    __syncthreads();

    for (int c = 0; c < NCH; ++c) {
        const int p = c & 1;
        if (c + 1 < NCH) STAGE(c + 1, p ^ 1);
        const char* gb = (const char*)gbuf[p];
        if (w < 6) {
            const int rbA = (tilid == 0) ? 0 : 32;
            const int rbB = (tilid == 2) ? 32 : 0;
            const int rA = rbA + l31, rB = rbB + l31;
            const int swA = (rA & 15) << 4, swB = (rB & 15) << 4;
            const char* mbase = (const char*)m2 + c*512 + hsel*16;
#pragma unroll
            for (int s8 = 0; s8 < 8; ++s8) {
                const int s = half*8 + s8;
                const int colbyte = s*32 + hsel*16;
                u32x4 fB = *(const u32x4*)(gb + rB*512 + (colbyte ^ swB));
                u32x4 fA;
                if (tilid == 1) fA = *(const u32x4*)(gb + rA*512 + (colbyte ^ swA));
                else            fA = fB;                       // diag tiles: reuse read
                u32x4 mkv = *(const u32x4*)(mbase + s*32);     // broadcast per half-wave
                fA = fA & mkv;                                  // mask A-side only (m^2=m)
                acc = __builtin_amdgcn_mfma_f32_32x32x16_bf16(
                        __builtin_bit_cast(bf16x8, fA),
                        __builtin_bit_cast(bf16x8, fB), acc, 0, 0, 0);
            }
        } else {
            const int cb0 = (w == 6) ? 0 : 32;
            const int l15 = lane & 15;
            const int g4 = lane >> 4;
            const int r0 = cb0 + l15, r1 = r0 + 16;
            const int sw0 = (r0 & 15) << 4, sw1 = (r1 & 15) << 4;
            const char* dr = (const char*)dsrow[p];
#pragma unroll
            for (int su = 0; su < 8; ++su) {
                const int colbyte = su*64 + g4*16;
                u32x4 dv = *(const u32x4*)(dr + colbyte);      // broadcast
                if (l15 != 0) dv = dv ^ dv;                    // A rows 1..15 = 0
                u32x4 f0 = *(const u32x4*)(gb + r0*512 + (colbyte ^ sw0));
                u32x4 f1 = *(const u32x4*)(gb + r1*512 + (colbyte ^ sw1));
                ua  = __builtin_amdgcn_mfma_f32_16x16x32_bf16(
                        __builtin_bit_cast(bf16x8, dv), __builtin_bit_cast(bf16x8, f0), ua, 0,0,0);
                ubv = __builtin_amdgcn_mfma_f32_16x16x32_bf16(
                        __builtin_bit_cast(bf16x8, dv), __builtin_bit_cast(bf16x8, f1), ubv, 0,0,0);
            }
        }
        __syncthreads();
    }

    // epilogue: combine n-halves, write A tiles + u
    float* red = (float*)&gbuf[0][0];
    if (w < 6 && half == 0) {
#pragma unroll
        for (int g = 0; g < 16; ++g) {
            int row = (g & 3) + 8*(g >> 2) + 4*hsel;          // 32x32 C/D layout (m74/m101)
            red[tilid*1024 + row*32 + l31] = acc[g];
        }
    }
    if (w >= 6 && lane < 16) {                                 // 16x16 D row0 = u
        const int cb0 = (w == 6) ? 0 : 32;
        Uf[b*KKV + cb0 + lane]      = ua[0];
        Uf[b*KKV + cb0 + 16 + lane] = ubv[0];
    }
    __syncthreads();
    if (w < 6 && half == 1) {
#pragma unroll
        for (int g = 0; g < 16; ++g) {
            int row = (g & 3) + 8*(g >> 2) + 4*hsel;
            float v = red[tilid*1024 + row*32 + l31] + acc[g];
            int gr = (tilid == 0) ? row : 32 + row;
            int gc = (tilid == 2) ? 32 + l31 : l31;
            Abuf[(size_t)b*4096 + gr*64 + gc] = v;
        }
    }
#undef STAGE
}

// ======= K3: single-wave register-resident Cholesky + solve + assembly =======
// One wave per batch; lane i owns row i of A and of L in registers. Own kernel
// => own register budget (launch_bounds(64,1) -> no spill of Lrow[64]).
__global__ __launch_bounds__(64, 1) void chol64(
    const float* __restrict__ Abuf, const float* __restrict__ Uf,
    const float* __restrict__ scal, float* __restrict__ out) {
    const int b = blockIdx.x;
    const int lane = threadIdx.x;          // 0..63
    const float* Arow = Abuf + (size_t)b * 4096 + lane * 64;

    float arow[64];
#pragma unroll
    for (int j4 = 0; j4 < 16; ++j4)
        *(float4*)(arow + j4 * 4) = *(const float4*)(Arow + j4 * 4);
    float ubr = Uf[b * 64 + lane];

    float Lrow[64];
    float dval = 1.f, invd = 0.f;
#pragma unroll
    for (int j = 0; j < 64; ++j) {
        // left-looking column j: a = A[lane][j] - sum_{k<j} L[lane][k]*L[j][k]
        float s0 = 0.f, s1 = 0.f, s2 = 0.f, s3 = 0.f;   // 4-way chain split
#pragma unroll
        for (int k = 0; k < (j & ~3); k += 4) {
            s0 += Lrow[k]     * rlane(Lrow[k],     j);
            s1 += Lrow[k + 1] * rlane(Lrow[k + 1], j);
            s2 += Lrow[k + 2] * rlane(Lrow[k + 2], j);
            s3 += Lrow[k + 3] * rlane(Lrow[k + 3], j);
        }
#pragma unroll
        for (int k = (j & ~3); k < j; ++k)
            s0 += Lrow[k] * rlane(Lrow[k], j);
        float a = arow[j] + ((lane == j) ? 1.0f : 0.0f) - ((s0 + s1) + (s2 + s3));
        float dv = rlane(a, j);                 // = Ljj^2 (lane j's value)
        float invs = rsqrtf(dv);
        if (lane == j) { dval = dv; invd = invs; }
        Lrow[j] = (lane > j) ? a * invs : 0.f;  // strict lower col j (diag excluded)
    }

    // forward solve L z = u ; z2 = ||z||^2 (wave-uniform via readlanes)
    float z2 = 0.f;
#pragma unroll
    for (int j = 0; j < 64; ++j) {
        float zj = rlane(ubr, j) * rlane(invd, j);
        z2 += zj * zj;
        ubr -= Lrow[j] * zj;                    // Lrow[j]=0 for lane<=j
    }

    // logdetA = sum_j log(Ljj^2): one log per lane + butterfly
    float ld = __logf(dval);
#pragma unroll
    for (int off = 32; off > 0; off >>= 1) ld += __shfl_xor(ld, off);

    if (lane == 0) {
        float uni = scal[b*5+0], wdd = scal[b*5+1], nb = scal[b*5+2],
              mlp = scal[b*5+3], extra = scal[b*5+4];
        const float LOG2PI = 1.8378770664093453f;
        out[b] = uni + extra - 0.5f * (nb * LOG2PI + mlp + ld + (wdd - z2));
    }
}

extern "C" void kernel_launch(void* const* d_in, const int* in_sizes, int n_in,
                              void* d_out, int out_size, void* d_ws, size_t ws_size,
                              hipStream_t stream) {
    const float* targets = (const float*)d_in[0];
    const float* rho     = (const float*)d_in[1];
    const float* qs      = (const float*)d_in[2];
    const float* means   = (const float*)d_in[3];
    const float* C       = (const float*)d_in[4];
    const float* psi     = (const float*)d_in[5];
    float* out = (float*)d_out;

    char* ws = (char*)d_ws;
    u16* Csbf  = (u16*)(ws);                                      // 512 KB
    u16* dsbf  = (u16*)(ws + 0x80000);                            // 2 MB
    u32* mask2 = (u32*)(ws + 0x280000);                           // 2 MB
    float* Abuf = (float*)(ws + 0x480000);                        // 4 MB
    float* Uf   = (float*)(ws + 0x880000);                        // 64 KB
    float* scal = (float*)(ws + 0x890000);                        // 5 KB

    prep<<<BBV + KKV, 256, 0, stream>>>(targets, rho, qs, means, C, psi,
                                        Csbf, dsbf, mask2, scal);
    gram<<<BBV, 512, 0, stream>>>(Csbf, dsbf, mask2, Abuf, Uf);
    chol64<<<BBV, 64, 0, stream>>>(Abuf, Uf, scal, out);
}

// Round 5
// 47.887 us; speedup vs baseline: 2.5318x; 1.0137x over previous
//
#include <hip/hip_runtime.h>
#include <math.h>

#define NNV 4096   // N
#define KKV 64     // K
#define BBV 256    // B
#define CHN 256    // n-chunk staged in LDS
#define NCH (NNV / CHN)

typedef unsigned short u16;
typedef unsigned int u32;
typedef u32  u32x4  __attribute__((ext_vector_type(4)));
typedef short bf16x8 __attribute__((ext_vector_type(8)));
typedef float f32x4  __attribute__((ext_vector_type(4)));
typedef float f32x16 __attribute__((ext_vector_type(16)));

__device__ inline u16 f2bf(float x) {           // RNE f32 -> bf16
    u32 u = __float_as_uint(x);
    u = u + 0x7FFFu + ((u >> 16) & 1u);
    return (u16)(u >> 16);
}

__device__ inline float rlane(float v, int l) { // wave-uniform readlane broadcast
    return __uint_as_float(__builtin_amdgcn_readlane(__float_as_uint(v), l));
}

// ================= K1: elementwise prep (+ Cs build in blocks 256..319) ===========
__global__ __launch_bounds__(256) void prep(
    const float* __restrict__ targets, const float* __restrict__ rho,
    const float* __restrict__ qs, const float* __restrict__ means,
    const float* __restrict__ C, const float* __restrict__ psi,
    u16* __restrict__ Csbf, u16* __restrict__ dsbf,
    u32* __restrict__ mask2, float* __restrict__ scal) {
    const int blk = blockIdx.x;
    const int t = threadIdx.x;

    if (blk >= BBV) {                    // Cs = C * rsqrt(psi), bf16, row-major [64][4096]
        const int k = blk - BBV;
        const float* Crow = C + (size_t)k * NNV;
        u16* Orow = Csbf + (size_t)k * NNV;
        const int base = t * 16;
#pragma unroll
        for (int j = 0; j < 16; j += 4) {
            float4 cv = *(const float4*)(Crow + base + j);
            float4 pv = *(const float4*)(psi + base + j);
            u32 w0 = (u32)f2bf(cv.x * rsqrtf(pv.x)) | ((u32)f2bf(cv.y * rsqrtf(pv.y)) << 16);
            u32 w1 = (u32)f2bf(cv.z * rsqrtf(pv.z)) | ((u32)f2bf(cv.w * rsqrtf(pv.w)) << 16);
            *(uint2*)(Orow + base + j) = make_uint2(w0, w1);
        }
        return;
    }

    __shared__ float sred[4][5];
    const int b = blk;
    const int lane = t & 63, wid = t >> 6;
    const float rho_s = rho[0];
    const float lrho = __logf(rho_s);
    const int base = t * 16;
    const float* tg = targets + (size_t)b * NNV + base;
    const float* qb = qs + (size_t)b * NNV + base;
    const float* mb = means + (size_t)b * NNV + base;
    const float* pb = psi + base;

    float tvv[16], qv[16], muv[16], pv[16];
#pragma unroll
    for (int j = 0; j < 16; j += 4) {
        *(float4*)(tvv + j) = *(const float4*)(tg + j);
        *(float4*)(qv + j)  = *(const float4*)(qb + j);
        *(float4*)(muv + j) = *(const float4*)(mb + j);
        *(float4*)(pv + j)  = *(const float4*)(pb + j);
    }

    float s_uni = 0.f, s_wdd = 0.f, s_nb = 0.f, s_mlp = 0.f, s_extra = 0.f;
    u16 dsv[16]; bool mk[16];
#pragma unroll
    for (int j = 0; j < 16; ++j) {
        bool m = tvv[j] >= rho_s;
        float ds = 0.f;
        if (m) {
            float y = __logf(tvv[j]);
            float d = y - muv[j];
            ds = d * rsqrtf(pv[j]);               // ds^2 = w*d^2
            s_wdd += ds * ds;
            s_nb += 1.f;
            s_mlp += __logf(pv[j]);
            s_extra += __logf(qv[j]) - y;
        } else {
            s_uni += __logf(1.f - qv[j]) - lrho;
        }
        dsv[j] = f2bf(ds);
        mk[j] = m;
    }
    u32 mw[8], dp[8];
#pragma unroll
    for (int i = 0; i < 8; ++i) {
        mw[i] = (mk[2*i] ? 0xFFFFu : 0u) | (mk[2*i+1] ? 0xFFFF0000u : 0u);
        dp[i] = (u32)dsv[2*i] | ((u32)dsv[2*i+1] << 16);
    }
    *(u32x4*)(dsbf + (size_t)b * NNV + base)     = ((u32x4*)dp)[0];
    *(u32x4*)(dsbf + (size_t)b * NNV + base + 8) = ((u32x4*)dp)[1];
    *(u32x4*)(mask2 + (size_t)b * (NNV/2) + t*8)     = ((u32x4*)mw)[0];
    *(u32x4*)(mask2 + (size_t)b * (NNV/2) + t*8 + 4) = ((u32x4*)mw)[1];

#pragma unroll
    for (int off = 32; off > 0; off >>= 1) {
        s_uni  += __shfl_down(s_uni, off);
        s_wdd  += __shfl_down(s_wdd, off);
        s_nb   += __shfl_down(s_nb, off);
        s_mlp  += __shfl_down(s_mlp, off);
        s_extra+= __shfl_down(s_extra, off);
    }
    if (lane == 0) {
        sred[wid][0] = s_uni; sred[wid][1] = s_wdd; sred[wid][2] = s_nb;
        sred[wid][3] = s_mlp; sred[wid][4] = s_extra;
    }
    __syncthreads();
    if (t == 0) {
        float a0=0,a1=0,a2=0,a3=0,a4=0;
#pragma unroll
        for (int w4 = 0; w4 < 4; ++w4) {
            a0 += sred[w4][0]; a1 += sred[w4][1]; a2 += sred[w4][2];
            a3 += sred[w4][3]; a4 += sred[w4][4];
        }
        scal[b*5+0]=a0; scal[b*5+1]=a1; scal[b*5+2]=a2; scal[b*5+3]=a3; scal[b*5+4]=a4;
    }
}

// ================= K2: per-batch Gram via MFMA, triple-buffered counted-vmcnt ===========
// G = [m ? Cs : 0 (64 rows); ds]; computes A00,A10,A11 (32x32 tiles) and u (row64).
__global__ __launch_bounds__(512) void gram(
    const u16* __restrict__ Csbf, const u16* __restrict__ dsbf,
    const u32* __restrict__ mask2g, float* __restrict__ Abuf, float* __restrict__ Uf) {
    __shared__ __align__(16) u16 gbuf[3][KKV * CHN];   // swizzled Cs chunk, 32 KB each
    __shared__ __align__(16) u16 dsrow[3][512];        // 1 KB each (upper 512 B = dup)
    __shared__ __align__(16) u32 m2[NNV / 2];          // packed bf16-pair masks, 8 KB

    const int b = blockIdx.x;
    const int t = threadIdx.x;
    const int lane = t & 63;
    const int w = t >> 6;
    const int half = w & 1;
    const int tilid = w >> 1;          // 0,1,2 = A00,A10,A11 ; 3 = u-waves
    const int l31 = lane & 31;
    const int hsel = lane >> 5;

    {   // stage full-batch mask words
        u32x4 v = *(const u32x4*)(mask2g + (size_t)b * (NNV/2) + t*4);
        *(u32x4*)(m2 + t*4) = v;
    }

    f32x16 acc;
#pragma unroll
    for (int i = 0; i < 16; ++i) acc[i] = 0.f;
    f32x4 ua, ubv;
#pragma unroll
    for (int i = 0; i < 4; ++i) { ua[i] = 0.f; ubv[i] = 0.f; }

// Every wave issues exactly 5 global_load_lds per STAGE (4 A-rows + 1 ds-row;
// ds-row is written identically by all 8 waves -> benign, keeps vmcnt uniform).
#define STAGE(cc, pp) do {                                                          \
    _Pragma("unroll")                                                               \
    for (int i_ = 0; i_ < 4; ++i_) {                                                \
        int beta0 = w*256 + i_*64;                                                  \
        int beta = beta0 + lane;                                                    \
        int r_ = beta >> 5, blkP = beta & 31;                                       \
        int blkS = blkP ^ (r_ & 15);   /* source pre-swizzle (m173 pattern) */      \
        const u16* src = Csbf + (size_t)r_ * NNV + (cc)*CHN + blkS*8;               \
        __builtin_amdgcn_global_load_lds(                                           \
            (const __attribute__((address_space(1))) void*)src,                     \
            (__attribute__((address_space(3))) void*)(&gbuf[pp][beta0*8]),          \
            16, 0, 0);                                                              \
    }                                                                               \
    {                                                                               \
        const u16* srcd = dsbf + (size_t)b * NNV + (cc)*CHN + (lane & 31)*8;        \
        __builtin_amdgcn_global_load_lds(                                           \
            (const __attribute__((address_space(1))) void*)srcd,                    \
            (__attribute__((address_space(3))) void*)(&dsrow[pp][0]),               \
            16, 0, 0);                                                              \
    }                                                                               \
} while (0)

    STAGE(0, 0);
    STAGE(1, 1);
    // wait stage-0 complete (stage-1's 5 loads may remain in flight) + m2 writes
    asm volatile("s_waitcnt vmcnt(5) lgkmcnt(0)" ::: "memory");
    __builtin_amdgcn_s_barrier();

#pragma unroll
    for (int c = 0; c < NCH; ++c) {
        const int p = c % 3;
        if (c + 2 < NCH) STAGE(c + 2, (c + 2) % 3);
        const char* gb = (const char*)gbuf[p];
        if (w < 6) {
            const int rbA = (tilid == 0) ? 0 : 32;
            const int rbB = (tilid == 2) ? 32 : 0;
            const int rA = rbA + l31, rB = rbB + l31;
            const int swA = (rA & 15) << 4, swB = (rB & 15) << 4;
            const char* mbase = (const char*)m2 + c*512 + hsel*16;
#pragma unroll
            for (int s8 = 0; s8 < 8; ++s8) {
                const int s = half*8 + s8;
                const int colbyte = s*32 + hsel*16;
                u32x4 fB = *(const u32x4*)(gb + rB*512 + (colbyte ^ swB));
                u32x4 fA;
                if (tilid == 1) fA = *(const u32x4*)(gb + rA*512 + (colbyte ^ swA));
                else            fA = fB;                       // diag tiles: reuse read
                u32x4 mkv = *(const u32x4*)(mbase + s*32);     // broadcast per half-wave
                fA = fA & mkv;                                  // mask A-side only (m^2=m)
                acc = __builtin_amdgcn_mfma_f32_32x32x16_bf16(
                        __builtin_bit_cast(bf16x8, fA),
                        __builtin_bit_cast(bf16x8, fB), acc, 0, 0, 0);
            }
        } else {
            const int cb0 = (w == 6) ? 0 : 32;
            const int l15 = lane & 15;
            const int g4 = lane >> 4;
            const int r0 = cb0 + l15, r1 = r0 + 16;
            const int sw0 = (r0 & 15) << 4, sw1 = (r1 & 15) << 4;
            const char* dr = (const char*)dsrow[p];
#pragma unroll
            for (int su = 0; su < 8; ++su) {
                const int colbyte = su*64 + g4*16;
                u32x4 dv = *(const u32x4*)(dr + colbyte);      // broadcast
                if (l15 != 0) dv = dv ^ dv;                    // A rows 1..15 = 0
                u32x4 f0 = *(const u32x4*)(gb + r0*512 + (colbyte ^ sw0));
                u32x4 f1 = *(const u32x4*)(gb + r1*512 + (colbyte ^ sw1));
                ua  = __builtin_amdgcn_mfma_f32_16x16x32_bf16(
                        __builtin_bit_cast(bf16x8, dv), __builtin_bit_cast(bf16x8, f0), ua, 0,0,0);
                ubv = __builtin_amdgcn_mfma_f32_16x16x32_bf16(
                        __builtin_bit_cast(bf16x8, dv), __builtin_bit_cast(bf16x8, f1), ubv, 0,0,0);
            }
        }
        // counted drain: need stage c+1 done; stage c+2 (5 loads) may stay in flight
        if (c + 2 < NCH) asm volatile("s_waitcnt vmcnt(5) lgkmcnt(0)" ::: "memory");
        else             asm volatile("s_waitcnt vmcnt(0) lgkmcnt(0)" ::: "memory");
        __builtin_amdgcn_s_barrier();
    }

    // epilogue: combine n-halves, write A tiles + u
    float* red = (float*)&gbuf[0][0];
    if (w < 6 && half == 0) {
#pragma unroll
        for (int g = 0; g < 16; ++g) {
            int row = (g & 3) + 8*(g >> 2) + 4*hsel;          // 32x32 C/D layout (m74/m101)
            red[tilid*1024 + row*32 + l31] = acc[g];
        }
    }
    if (w >= 6 && lane < 16) {                                 // 16x16 D row0 = u
        const int cb0 = (w == 6) ? 0 : 32;
        Uf[b*KKV + cb0 + lane]      = ua[0];
        Uf[b*KKV + cb0 + 16 + lane] = ubv[0];
    }
    __syncthreads();
    if (w < 6 && half == 1) {
#pragma unroll
        for (int g = 0; g < 16; ++g) {
            int row = (g & 3) + 8*(g >> 2) + 4*hsel;
            float v = red[tilid*1024 + row*32 + l31] + acc[g];
            int gr = (tilid == 0) ? row : 32 + row;
            int gc = (tilid == 2) ? 32 + l31 : l31;
            Abuf[(size_t)b*4096 + gr*64 + gc] = v;
        }
    }
#undef STAGE
}

// ======= K3: single-wave register-resident Cholesky + solve + assembly =======
__global__ __launch_bounds__(64, 1) void chol64(
    const float* __restrict__ Abuf, const float* __restrict__ Uf,
    const float* __restrict__ scal, float* __restrict__ out) {
    const int b = blockIdx.x;
    const int lane = threadIdx.x;          // 0..63
    const float* Arow = Abuf + (size_t)b * 4096 + lane * 64;

    float arow[64];
#pragma unroll
    for (int j4 = 0; j4 < 16; ++j4)
        *(float4*)(arow + j4 * 4) = *(const float4*)(Arow + j4 * 4);
    float ubr = Uf[b * 64 + lane];

    float Lrow[64];
    float dval = 1.f, invd = 0.f;
#pragma unroll
    for (int j = 0; j < 64; ++j) {
        float s0 = 0.f, s1 = 0.f, s2 = 0.f, s3 = 0.f;   // 4-way chain split
#pragma unroll
        for (int k = 0; k < (j & ~3); k += 4) {
            s0 += Lrow[k]     * rlane(Lrow[k],     j);
            s1 += Lrow[k + 1] * rlane(Lrow[k + 1], j);
            s2 += Lrow[k + 2] * rlane(Lrow[k + 2], j);
            s3 += Lrow[k + 3] * rlane(Lrow[k + 3], j);
        }
#pragma unroll
        for (int k = (j & ~3); k < j; ++k)
            s0 += Lrow[k] * rlane(Lrow[k], j);
        float a = arow[j] + ((lane == j) ? 1.0f : 0.0f) - ((s0 + s1) + (s2 + s3));
        float dv = rlane(a, j);                 // = Ljj^2 (lane j's value)
        float invs = rsqrtf(dv);
        if (lane == j) { dval = dv; invd = invs; }
        Lrow[j] = (lane > j) ? a * invs : 0.f;  // strict lower col j (diag excluded)
    }

    // forward solve L z = u ; z2 = ||z||^2 (wave-uniform via readlanes)
    float z2 = 0.f;
#pragma unroll
    for (int j = 0; j < 64; ++j) {
        float zj = rlane(ubr, j) * rlane(invd, j);
        z2 += zj * zj;
        ubr -= Lrow[j] * zj;                    // Lrow[j]=0 for lane<=j
    }

    // logdetA = sum_j log(Ljj^2): one log per lane + butterfly
    float ld = __logf(dval);
#pragma unroll
    for (int off = 32; off > 0; off >>= 1) ld += __shfl_xor(ld, off);

    if (lane == 0) {
        float uni = scal[b*5+0], wdd = scal[b*5+1], nb = scal[b*5+2],
              mlp = scal[b*5+3], extra = scal[b*5+4];
        const float LOG2PI = 1.8378770664093453f;
        out[b] = uni + extra - 0.5f * (nb * LOG2PI + mlp + ld + (wdd - z2));
    }
}

extern "C" void kernel_launch(void* const* d_in, const int* in_sizes, int n_in,
                              void* d_out, int out_size, void* d_ws, size_t ws_size,
                              hipStream_t stream) {
    const float* targets = (const float*)d_in[0];
    const float* rho     = (const float*)d_in[1];
    const float* qs      = (const float*)d_in[2];
    const float* means   = (const float*)d_in[3];
    const float* C       = (const float*)d_in[4];
    const float* psi     = (const float*)d_in[5];
    float* out = (float*)d_out;

    char* ws = (char*)d_ws;
    u16* Csbf  = (u16*)(ws);                                      // 512 KB
    u16* dsbf  = (u16*)(ws + 0x80000);                            // 2 MB
    u32* mask2 = (u32*)(ws + 0x280000);                           // 2 MB
    float* Abuf = (float*)(ws + 0x480000);                        // 4 MB
    float* Uf   = (float*)(ws + 0x880000);                        // 64 KB
    float* scal = (float*)(ws + 0x890000);                        // 5 KB

    prep<<<BBV + KKV, 256, 0, stream>>>(targets, rho, qs, means, C, psi,
                                        Csbf, dsbf, mask2, scal);
    gram<<<BBV, 512, 0, stream>>>(Csbf, dsbf, mask2, Abuf, Uf);
    chol64<<<BBV, 64, 0, stream>>>(Abuf, Uf, scal, out);
}

// Round 6
// 45.276 us; speedup vs baseline: 2.6779x; 1.0577x over previous
//
#include <hip/hip_runtime.h>
#include <math.h>

#define NNV 4096   // N
#define KKV 64     // K
#define BBV 256    // B
#define CHN 256    // n-chunk staged in LDS
#define NCH (NNV / CHN)

typedef unsigned short u16;
typedef unsigned int u32;
typedef u32  u32x4  __attribute__((ext_vector_type(4)));
typedef short bf16x8 __attribute__((ext_vector_type(8)));
typedef float f32x4  __attribute__((ext_vector_type(4)));
typedef float f32x16 __attribute__((ext_vector_type(16)));

__device__ inline u16 f2bf(float x) {           // RNE f32 -> bf16
    u32 u = __float_as_uint(x);
    u = u + 0x7FFFu + ((u >> 16) & 1u);
    return (u16)(u >> 16);
}

__device__ inline float rlane(float v, int l) { // wave-uniform readlane broadcast
    return __uint_as_float(__builtin_amdgcn_readlane(__float_as_uint(v), l));
}

// ================= K1: elementwise prep (+ Cs build in blocks 256..319) ===========
__global__ __launch_bounds__(256) void prep(
    const float* __restrict__ targets, const float* __restrict__ rho,
    const float* __restrict__ qs, const float* __restrict__ means,
    const float* __restrict__ C, const float* __restrict__ psi,
    u16* __restrict__ Csbf, u16* __restrict__ dsbf,
    u32* __restrict__ mask2, float* __restrict__ scal) {
    const int blk = blockIdx.x;
    const int t = threadIdx.x;

    if (blk >= BBV) {                    // Cs = C * rsqrt(psi), bf16, row-major [64][4096]
        const int k = blk - BBV;
        const float* Crow = C + (size_t)k * NNV;
        u16* Orow = Csbf + (size_t)k * NNV;
        const int base = t * 16;
#pragma unroll
        for (int j = 0; j < 16; j += 4) {
            float4 cv = *(const float4*)(Crow + base + j);
            float4 pv = *(const float4*)(psi + base + j);
            u32 w0 = (u32)f2bf(cv.x * rsqrtf(pv.x)) | ((u32)f2bf(cv.y * rsqrtf(pv.y)) << 16);
            u32 w1 = (u32)f2bf(cv.z * rsqrtf(pv.z)) | ((u32)f2bf(cv.w * rsqrtf(pv.w)) << 16);
            *(uint2*)(Orow + base + j) = make_uint2(w0, w1);
        }
        return;
    }

    __shared__ float sred[4][5];
    const int b = blk;
    const int lane = t & 63, wid = t >> 6;
    const float rho_s = rho[0];
    const float lrho = __logf(rho_s);
    const int base = t * 16;
    const float* tg = targets + (size_t)b * NNV + base;
    const float* qb = qs + (size_t)b * NNV + base;
    const float* mb = means + (size_t)b * NNV + base;
    const float* pb = psi + base;

    float tvv[16], qv[16], muv[16], pv[16];
#pragma unroll
    for (int j = 0; j < 16; j += 4) {
        *(float4*)(tvv + j) = *(const float4*)(tg + j);
        *(float4*)(qv + j)  = *(const float4*)(qb + j);
        *(float4*)(muv + j) = *(const float4*)(mb + j);
        *(float4*)(pv + j)  = *(const float4*)(pb + j);
    }

    float s_uni = 0.f, s_wdd = 0.f, s_nb = 0.f, s_mlp = 0.f, s_extra = 0.f;
    u16 dsv[16]; bool mk[16];
#pragma unroll
    for (int j = 0; j < 16; ++j) {
        bool m = tvv[j] >= rho_s;
        float ds = 0.f;
        if (m) {
            float y = __logf(tvv[j]);
            float d = y - muv[j];
            ds = d * rsqrtf(pv[j]);               // ds^2 = w*d^2
            s_wdd += ds * ds;
            s_nb += 1.f;
            s_mlp += __logf(pv[j]);
            s_extra += __logf(qv[j]) - y;
        } else {
            s_uni += __logf(1.f - qv[j]) - lrho;
        }
        dsv[j] = f2bf(ds);
        mk[j] = m;
    }
    u32 mw[8], dp[8];
#pragma unroll
    for (int i = 0; i < 8; ++i) {
        mw[i] = (mk[2*i] ? 0xFFFFu : 0u) | (mk[2*i+1] ? 0xFFFF0000u : 0u);
        dp[i] = (u32)dsv[2*i] | ((u32)dsv[2*i+1] << 16);
    }
    *(u32x4*)(dsbf + (size_t)b * NNV + base)     = ((u32x4*)dp)[0];
    *(u32x4*)(dsbf + (size_t)b * NNV + base + 8) = ((u32x4*)dp)[1];
    *(u32x4*)(mask2 + (size_t)b * (NNV/2) + t*8)     = ((u32x4*)mw)[0];
    *(u32x4*)(mask2 + (size_t)b * (NNV/2) + t*8 + 4) = ((u32x4*)mw)[1];

#pragma unroll
    for (int off = 32; off > 0; off >>= 1) {
        s_uni  += __shfl_down(s_uni, off);
        s_wdd  += __shfl_down(s_wdd, off);
        s_nb   += __shfl_down(s_nb, off);
        s_mlp  += __shfl_down(s_mlp, off);
        s_extra+= __shfl_down(s_extra, off);
    }
    if (lane == 0) {
        sred[wid][0] = s_uni; sred[wid][1] = s_wdd; sred[wid][2] = s_nb;
        sred[wid][3] = s_mlp; sred[wid][4] = s_extra;
    }
    __syncthreads();
    if (t == 0) {
        float a0=0,a1=0,a2=0,a3=0,a4=0;
#pragma unroll
        for (int w4 = 0; w4 < 4; ++w4) {
            a0 += sred[w4][0]; a1 += sred[w4][1]; a2 += sred[w4][2];
            a3 += sred[w4][3]; a4 += sred[w4][4];
        }
        scal[b*5+0]=a0; scal[b*5+1]=a1; scal[b*5+2]=a2; scal[b*5+3]=a3; scal[b*5+4]=a4;
    }
}

// ========== K2: Gram via MFMA — 2 batches/block share Cs reads, n-split in 2 ==========
// Block (pair,nhalf) processes batches {2*pair, 2*pair+1} over n in [nhalf*2048, ...+2048).
// Writes partial A, u; chol64 sums the two n-half partials.
__global__ __launch_bounds__(512, 2) void gram(
    const u16* __restrict__ Csbf, const u16* __restrict__ dsbf,
    const u32* __restrict__ mask2g, float* __restrict__ Apart, float* __restrict__ Upart) {
    __shared__ __align__(16) u16 gbuf[3][KKV * CHN];   // swizzled Cs chunk, 32 KB each
    __shared__ __align__(16) u16 dsrow[2][3][512];     // per-batch ds rows (upper 512B dup)
    __shared__ __align__(16) u32 m2[2][NNV / 2];       // per-batch packed masks, 8 KB each

    const int bid = blockIdx.x;
    const int nhalf = bid & 1;
    const int pair = bid >> 1;
    const int b0 = pair * 2, b1 = b0 + 1;
    const int c0 = nhalf * (NCH / 2);    // first chunk of this block's n-range

    const int t = threadIdx.x;
    const int lane = t & 63;
    const int w = t >> 6;
    const int half = w & 1;
    const int tilid = w >> 1;          // 0,1,2 = A00,A10,A11 ; 3 = u-waves
    const int l31 = lane & 31;
    const int hsel = lane >> 5;

    {   // stage both batches' mask words (full 8 KB each; only our half is read)
        u32x4 v0 = *(const u32x4*)(mask2g + (size_t)b0 * (NNV/2) + t*4);
        *(u32x4*)(&m2[0][t*4]) = v0;
        u32x4 v1 = *(const u32x4*)(mask2g + (size_t)b1 * (NNV/2) + t*4);
        *(u32x4*)(&m2[1][t*4]) = v1;
    }

    f32x16 acc0, acc1;
#pragma unroll
    for (int i = 0; i < 16; ++i) { acc0[i] = 0.f; acc1[i] = 0.f; }
    f32x4 ua0, ub0, ua1, ub1;
#pragma unroll
    for (int i = 0; i < 4; ++i) { ua0[i] = 0.f; ub0[i] = 0.f; ua1[i] = 0.f; ub1[i] = 0.f; }

// Every wave issues exactly 6 global_load_lds per STAGE (4 Cs rows + 2 ds-rows;
// ds-rows written identically by all 8 waves -> benign, keeps vmcnt uniform).
#define STAGE(cc, pp) do {                                                          \
    _Pragma("unroll")                                                               \
    for (int i_ = 0; i_ < 4; ++i_) {                                                \
        int beta0 = w*256 + i_*64;                                                  \
        int beta = beta0 + lane;                                                    \
        int r_ = beta >> 5, blkP = beta & 31;                                       \
        int blkS = blkP ^ (r_ & 15);   /* source pre-swizzle (m173 pattern) */      \
        const u16* src = Csbf + (size_t)r_ * NNV + (cc)*CHN + blkS*8;               \
        __builtin_amdgcn_global_load_lds(                                           \
            (const __attribute__((address_space(1))) void*)src,                     \
            (__attribute__((address_space(3))) void*)(&gbuf[pp][beta0*8]),          \
            16, 0, 0);                                                              \
    }                                                                               \
    {                                                                               \
        const u16* s0_ = dsbf + (size_t)b0 * NNV + (cc)*CHN + (lane & 31)*8;        \
        __builtin_amdgcn_global_load_lds(                                           \
            (const __attribute__((address_space(1))) void*)s0_,                     \
            (__attribute__((address_space(3))) void*)(&dsrow[0][pp][0]),            \
            16, 0, 0);                                                              \
        const u16* s1_ = dsbf + (size_t)b1 * NNV + (cc)*CHN + (lane & 31)*8;        \
        __builtin_amdgcn_global_load_lds(                                           \
            (const __attribute__((address_space(1))) void*)s1_,                     \
            (__attribute__((address_space(3))) void*)(&dsrow[1][pp][0]),            \
            16, 0, 0);                                                              \
    }                                                                               \
} while (0)

    STAGE(c0 + 0, 0);
    STAGE(c0 + 1, 1);
    // wait stage-0 complete (stage-1's 6 loads may remain in flight) + m2 writes
    asm volatile("s_waitcnt vmcnt(6) lgkmcnt(0)" ::: "memory");
    __builtin_amdgcn_s_barrier();

#pragma unroll
    for (int cl = 0; cl < NCH / 2; ++cl) {
        const int c = c0 + cl;
        const int p = cl % 3;
        if (cl + 2 < NCH / 2) STAGE(c0 + cl + 2, (cl + 2) % 3);
        const char* gb = (const char*)gbuf[p];
        if (w < 6) {
            const int rbA = (tilid == 0) ? 0 : 32;
            const int rbB = (tilid == 2) ? 32 : 0;
            const int rA = rbA + l31, rB = rbB + l31;
            const int swA = (rA & 15) << 4, swB = (rB & 15) << 4;
            const char* mb0 = (const char*)&m2[0][0] + c*512 + hsel*16;
            const char* mb1 = (const char*)&m2[1][0] + c*512 + hsel*16;
#pragma unroll
            for (int s8 = 0; s8 < 8; ++s8) {
                const int s = half*8 + s8;
                const int colbyte = s*32 + hsel*16;
                u32x4 fB = *(const u32x4*)(gb + rB*512 + (colbyte ^ swB));
                u32x4 fAr;
                if (tilid == 1) fAr = *(const u32x4*)(gb + rA*512 + (colbyte ^ swA));
                else            fAr = fB;                      // diag tiles: reuse read
                u32x4 mk0 = *(const u32x4*)(mb0 + s*32);       // broadcast per half-wave
                u32x4 mk1 = *(const u32x4*)(mb1 + s*32);
                u32x4 fA0 = fAr & mk0;                         // mask A-side only (m^2=m)
                u32x4 fA1 = fAr & mk1;
                acc0 = __builtin_amdgcn_mfma_f32_32x32x16_bf16(
                        __builtin_bit_cast(bf16x8, fA0),
                        __builtin_bit_cast(bf16x8, fB), acc0, 0, 0, 0);
                acc1 = __builtin_amdgcn_mfma_f32_32x32x16_bf16(
                        __builtin_bit_cast(bf16x8, fA1),
                        __builtin_bit_cast(bf16x8, fB), acc1, 0, 0, 0);
            }
        } else {
            const int cb0 = (w == 6) ? 0 : 32;
            const int l15 = lane & 15;
            const int g4 = lane >> 4;
            const int r0 = cb0 + l15, r1 = r0 + 16;
            const int sw0 = (r0 & 15) << 4, sw1 = (r1 & 15) << 4;
            const char* dr0 = (const char*)&dsrow[0][p][0];
            const char* dr1 = (const char*)&dsrow[1][p][0];
#pragma unroll
            for (int su = 0; su < 8; ++su) {
                const int colbyte = su*64 + g4*16;
                u32x4 dv0 = *(const u32x4*)(dr0 + colbyte);    // broadcast
                u32x4 dv1 = *(const u32x4*)(dr1 + colbyte);
                if (l15 != 0) { dv0 = dv0 ^ dv0; dv1 = dv1 ^ dv1; }  // A rows 1..15 = 0
                u32x4 f0 = *(const u32x4*)(gb + r0*512 + (colbyte ^ sw0));
                u32x4 f1 = *(const u32x4*)(gb + r1*512 + (colbyte ^ sw1));
                ua0 = __builtin_amdgcn_mfma_f32_16x16x32_bf16(
                        __builtin_bit_cast(bf16x8, dv0), __builtin_bit_cast(bf16x8, f0), ua0, 0,0,0);
                ub0 = __builtin_amdgcn_mfma_f32_16x16x32_bf16(
                        __builtin_bit_cast(bf16x8, dv0), __builtin_bit_cast(bf16x8, f1), ub0, 0,0,0);
                ua1 = __builtin_amdgcn_mfma_f32_16x16x32_bf16(
                        __builtin_bit_cast(bf16x8, dv1), __builtin_bit_cast(bf16x8, f0), ua1, 0,0,0);
                ub1 = __builtin_amdgcn_mfma_f32_16x16x32_bf16(
                        __builtin_bit_cast(bf16x8, dv1), __builtin_bit_cast(bf16x8, f1), ub1, 0,0,0);
            }
        }
        // counted drain: need stage cl+1 done; stage cl+2 (6 loads) may stay in flight
        if (cl + 2 < NCH / 2) asm volatile("s_waitcnt vmcnt(6) lgkmcnt(0)" ::: "memory");
        else                  asm volatile("s_waitcnt vmcnt(0) lgkmcnt(0)" ::: "memory");
        __builtin_amdgcn_s_barrier();
    }

    // epilogue: combine s-halves, write partial A tiles + u for both batches
    float* red0 = (float*)&gbuf[0][0];     // 12 KB used
    float* red1 = (float*)&gbuf[1][0];
    if (w < 6 && half == 0) {
#pragma unroll
        for (int g = 0; g < 16; ++g) {
            int row = (g & 3) + 8*(g >> 2) + 4*hsel;          // 32x32 C/D layout (m74/m101)
            red0[tilid*1024 + row*32 + l31] = acc0[g];
            red1[tilid*1024 + row*32 + l31] = acc1[g];
        }
    }
    if (w >= 6 && lane < 16) {                                 // 16x16 D row0 = u
        const int cb0 = (w == 6) ? 0 : 32;
        float* U0 = Upart + ((size_t)nhalf * BBV + b0) * KKV;
        float* U1 = Upart + ((size_t)nhalf * BBV + b1) * KKV;
        U0[cb0 + lane]      = ua0[0];
        U0[cb0 + 16 + lane] = ub0[0];
        U1[cb0 + lane]      = ua1[0];
        U1[cb0 + 16 + lane] = ub1[0];
    }
    __syncthreads();
    if (w < 6 && half == 1) {
        float* A0 = Apart + ((size_t)nhalf * BBV + b0) * 4096;
        float* A1 = Apart + ((size_t)nhalf * BBV + b1) * 4096;
#pragma unroll
        for (int g = 0; g < 16; ++g) {
            int row = (g & 3) + 8*(g >> 2) + 4*hsel;
            int gr = (tilid == 0) ? row : 32 + row;
            int gc = (tilid == 2) ? 32 + l31 : l31;
            A0[gr*64 + gc] = red0[tilid*1024 + row*32 + l31] + acc0[g];
            A1[gr*64 + gc] = red1[tilid*1024 + row*32 + l31] + acc1[g];
        }
    }
#undef STAGE
}

// ======= K3: single-wave register-resident Cholesky + solve + assembly =======
__global__ __launch_bounds__(64, 1) void chol64(
    const float* __restrict__ Apart, const float* __restrict__ Upart,
    const float* __restrict__ scal, float* __restrict__ out) {
    const int b = blockIdx.x;
    const int lane = threadIdx.x;          // 0..63
    const float* Ar0 = Apart + (size_t)b * 4096 + lane * 64;
    const float* Ar1 = Apart + ((size_t)BBV + b) * 4096 + lane * 64;

    float arow[64];
#pragma unroll
    for (int j4 = 0; j4 < 16; ++j4) {
        float4 v0 = *(const float4*)(Ar0 + j4 * 4);
        float4 v1 = *(const float4*)(Ar1 + j4 * 4);
        arow[j4*4+0] = v0.x + v1.x;
        arow[j4*4+1] = v0.y + v1.y;
        arow[j4*4+2] = v0.z + v1.z;
        arow[j4*4+3] = v0.w + v1.w;
    }
    float ubr = Upart[b * 64 + lane] + Upart[(BBV + b) * 64 + lane];

    float Lrow[64];
    float dval = 1.f, invd = 0.f;
#pragma unroll
    for (int j = 0; j < 64; ++j) {
        float s0 = 0.f, s1 = 0.f, s2 = 0.f, s3 = 0.f;   // 4-way chain split
#pragma unroll
        for (int k = 0; k < (j & ~3); k += 4) {
            s0 += Lrow[k]     * rlane(Lrow[k],     j);
            s1 += Lrow[k + 1] * rlane(Lrow[k + 1], j);
            s2 += Lrow[k + 2] * rlane(Lrow[k + 2], j);
            s3 += Lrow[k + 3] * rlane(Lrow[k + 3], j);
        }
#pragma unroll
        for (int k = (j & ~3); k < j; ++k)
            s0 += Lrow[k] * rlane(Lrow[k], j);
        float a = arow[j] + ((lane == j) ? 1.0f : 0.0f) - ((s0 + s1) + (s2 + s3));
        float dv = rlane(a, j);                 // = Ljj^2 (lane j's value)
        float invs = rsqrtf(dv);
        if (lane == j) { dval = dv; invd = invs; }
        Lrow[j] = (lane > j) ? a * invs : 0.f;  // strict lower col j (diag excluded)
    }

    // forward solve L z = u ; z2 = ||z||^2 (wave-uniform via readlanes)
    float z2 = 0.f;
#pragma unroll
    for (int j = 0; j < 64; ++j) {
        float zj = rlane(ubr, j) * rlane(invd, j);
        z2 += zj * zj;
        ubr -= Lrow[j] * zj;                    // Lrow[j]=0 for lane<=j
    }

    // logdetA = sum_j log(Ljj^2): one log per lane + butterfly
    float ld = __logf(dval);
#pragma unroll
    for (int off = 32; off > 0; off >>= 1) ld += __shfl_xor(ld, off);

    if (lane == 0) {
        float uni = scal[b*5+0], wdd = scal[b*5+1], nb = scal[b*5+2],
              mlp = scal[b*5+3], extra = scal[b*5+4];
        const float LOG2PI = 1.8378770664093453f;
        out[b] = uni + extra - 0.5f * (nb * LOG2PI + mlp + ld + (wdd - z2));
    }
}

extern "C" void kernel_launch(void* const* d_in, const int* in_sizes, int n_in,
                              void* d_out, int out_size, void* d_ws, size_t ws_size,
                              hipStream_t stream) {
    const float* targets = (const float*)d_in[0];
    const float* rho     = (const float*)d_in[1];
    const float* qs      = (const float*)d_in[2];
    const float* means   = (const float*)d_in[3];
    const float* C       = (const float*)d_in[4];
    const float* psi     = (const float*)d_in[5];
    float* out = (float*)d_out;

    char* ws = (char*)d_ws;
    u16* Csbf   = (u16*)(ws);                                     // 512 KB
    u16* dsbf   = (u16*)(ws + 0x80000);                           // 2 MB
    u32* mask2  = (u32*)(ws + 0x280000);                          // 2 MB
    float* Apart = (float*)(ws + 0x480000);                       // 8 MB (2 n-halves)
    float* Upart = (float*)(ws + 0xC80000);                       // 128 KB (2 n-halves)
    float* scal  = (float*)(ws + 0xCC0000);                       // 5 KB

    prep<<<BBV + KKV, 256, 0, stream>>>(targets, rho, qs, means, C, psi,
                                        Csbf, dsbf, mask2, scal);
    gram<<<BBV, 512, 0, stream>>>(Csbf, dsbf, mask2, Apart, Upart);
    chol64<<<BBV, 64, 0, stream>>>(Apart, Upart, scal, out);
}